// Round 1
// baseline (548.431 us; speedup 1.0000x reference)
//
#include <hip/hip_runtime.h>

#define VOCAB 50000
#define VDIM 256
#define TOPICS 512

// float4 component access with compile-time-foldable index (avoid scratch).
__device__ __forceinline__ float f4get(const float4 v, int i) {
  switch (i) { case 0: return v.x; case 1: return v.y; case 2: return v.z; default: return v.w; }
}

// ---------------------------------------------------------------------------
// Precompute:
//   tBT[d][t] = sum_k B[d,k] * t2v[t,k]     (d<256 rows, t<512 cols)  = (t2v@B^T)^T
//   AtT[t][d] = sum_k A[d,k] * t2v[t,k]     (t<512 rows, d<256 cols)  = (A@t2v^T)^T
// Block b<256: one tBT row (stage B[b,:] in LDS, 512 threads = t).
// Block 256+t: one AtT row (stage t2v[t,:] in LDS, 256 threads = d).
// ---------------------------------------------------------------------------
__global__ __launch_bounds__(512) void precompute_kernel(
    const float* __restrict__ t2v, const float* __restrict__ A,
    const float* __restrict__ B, float* __restrict__ tBT, float* __restrict__ AtT)
{
  __shared__ float row[256];
  const int b = blockIdx.x;
  const int tid = threadIdx.x;
  if (b < VDIM) {
    if (tid < 256) row[tid] = B[(size_t)b * 256 + tid];
    __syncthreads();
    const float4* rv = (const float4*)row;
    const float4* tv = (const float4*)(t2v + (size_t)tid * 256);
    float acc = 0.f;
#pragma unroll 8
    for (int k = 0; k < 64; ++k) {
      float4 r = rv[k]; float4 x = tv[k];
      acc += r.x * x.x + r.y * x.y + r.z * x.z + r.w * x.w;
    }
    tBT[(size_t)b * TOPICS + tid] = acc;
  } else {
    const int t = b - VDIM;
    if (tid < 256) row[tid] = t2v[(size_t)t * 256 + tid];
    __syncthreads();
    if (tid < 256) {
      const float4* rv = (const float4*)row;
      const float4* av = (const float4*)(A + (size_t)tid * 256);
      float acc = 0.f;
#pragma unroll 8
      for (int k = 0; k < 64; ++k) {
        float4 r = rv[k]; float4 x = av[k];
        acc += r.x * x.x + r.y * x.y + r.z * x.z + r.w * x.w;
      }
      AtT[(size_t)t * VDIM + tid] = acc;
    }
  }
}

// ---------------------------------------------------------------------------
// Main fused kernel: 16 vocab columns per block, 256 threads (4 waves).
//   phase 0  : stage W[v][d] = w2v[vb+v][d] in LDS
//   phase 1  : S[v][t] = s[t, vb+v] = sum_d tBT[d][t] * W[v][d]
//   phase 1.5: write s tile to global (scalar dwords; s base is odd-offset)
//   phase 2  : softmax over t per column (wave-parallel, shfl_xor reduce)
//   phase 2.5: write alpha tile to global (float4)
//   phase 3  : mu[d][v] = sum_t AtT[t][d] * alpha[t][v]; P = (1/sigma)*sum_d diff^2
// ---------------------------------------------------------------------------
__global__ __launch_bounds__(256) void fused_main(
    const float* __restrict__ w2v, const float* __restrict__ tBT,
    const float* __restrict__ AtT, const float* __restrict__ sigma,
    float* __restrict__ out_alpha, float* __restrict__ out_P,
    float* __restrict__ out_s)
{
  __shared__ float W[16][260];   // pitch 260: b128-aligned, 2-way max on reads
  __shared__ float S[16][520];   // [v][t], pitch 520 (16B-aligned rows)
  __shared__ float red[16][4];

  const int tid = threadIdx.x;
  const int vb = blockIdx.x * 16;

  // ---- phase 0: stage W ----
#pragma unroll
  for (int r = 0; r < 4; ++r) {
    int idx = tid + 256 * r;
    int v = idx >> 6;
    int k4 = (idx & 63) << 2;
    float4 x = *(const float4*)(w2v + (size_t)(vb + v) * 256 + k4);
    *(float4*)&W[v][k4] = x;
  }
  __syncthreads();

  // ---- phase 1: S[v][t] ----
  const int tg = tid >> 2, vg = tid & 3;
  const int t0 = tg << 3, v0 = vg << 2;   // 8 topics x 4 vocab per thread
  float acc[8][4];
#pragma unroll
  for (int i = 0; i < 8; ++i)
#pragma unroll
    for (int j = 0; j < 4; ++j) acc[i][j] = 0.f;

  for (int d4 = 0; d4 < 64; ++d4) {
    float4 wv[4];
#pragma unroll
    for (int j = 0; j < 4; ++j) wv[j] = *(const float4*)&W[v0 + j][d4 << 2];
    float4 tb0[4], tb1[4];
#pragma unroll
    for (int dd = 0; dd < 4; ++dd) {
      const float* p = tBT + (size_t)((d4 << 2) + dd) * TOPICS + t0;
      tb0[dd] = *(const float4*)p;
      tb1[dd] = *(const float4*)(p + 4);
    }
#pragma unroll
    for (int dd = 0; dd < 4; ++dd) {
#pragma unroll
      for (int j = 0; j < 4; ++j) {
        float wc = f4get(wv[j], dd);
        acc[0][j] = fmaf(tb0[dd].x, wc, acc[0][j]);
        acc[1][j] = fmaf(tb0[dd].y, wc, acc[1][j]);
        acc[2][j] = fmaf(tb0[dd].z, wc, acc[2][j]);
        acc[3][j] = fmaf(tb0[dd].w, wc, acc[3][j]);
        acc[4][j] = fmaf(tb1[dd].x, wc, acc[4][j]);
        acc[5][j] = fmaf(tb1[dd].y, wc, acc[5][j]);
        acc[6][j] = fmaf(tb1[dd].z, wc, acc[6][j]);
        acc[7][j] = fmaf(tb1[dd].w, wc, acc[7][j]);
      }
    }
  }
#pragma unroll
  for (int j = 0; j < 4; ++j) {
    *(float4*)&S[v0 + j][t0]     = make_float4(acc[0][j], acc[1][j], acc[2][j], acc[3][j]);
    *(float4*)&S[v0 + j][t0 + 4] = make_float4(acc[4][j], acc[5][j], acc[6][j], acc[7][j]);
  }
  __syncthreads();

  // ---- phase 1.5: write s tile (s region starts at odd dword -> scalar stores) ----
  {
    const int vi = tid & 15, tt = tid >> 4;
#pragma unroll 4
    for (int it = 0; it < 32; ++it) {
      int t = tt + (it << 4);
      out_s[(size_t)t * VOCAB + vb + vi] = S[vi][t];
    }
  }
  __syncthreads();

  // ---- phase 2: softmax over t (dim 0) per column; each wave owns 4 columns ----
  const int wave = tid >> 6, lane = tid & 63;
#pragma unroll
  for (int c = 0; c < 4; ++c) {
    const int v = (wave << 2) + c;
    float sv[8];
#pragma unroll
    for (int i = 0; i < 8; ++i) sv[i] = S[v][lane + (i << 6)];
    float m = sv[0];
#pragma unroll
    for (int i = 1; i < 8; ++i) m = fmaxf(m, sv[i]);
#pragma unroll
    for (int off = 32; off > 0; off >>= 1) m = fmaxf(m, __shfl_xor(m, off));
    float sum = 0.f;
#pragma unroll
    for (int i = 0; i < 8; ++i) { sv[i] = __expf(sv[i] - m); sum += sv[i]; }
#pragma unroll
    for (int off = 32; off > 0; off >>= 1) sum += __shfl_xor(sum, off);
    const float inv = 1.0f / sum;
#pragma unroll
    for (int i = 0; i < 8; ++i) S[v][lane + (i << 6)] = sv[i] * inv;
  }
  __syncthreads();

  // ---- phase 2.5: write alpha tile (float4, alpha base is 16B aligned) ----
  {
    const int vq = tid & 3, tt = tid >> 2;
#pragma unroll 2
    for (int it = 0; it < 8; ++it) {
      int t = tt + (it << 6);
      float4 a;
      a.x = S[(vq << 2) + 0][t];
      a.y = S[(vq << 2) + 1][t];
      a.z = S[(vq << 2) + 2][t];
      a.w = S[(vq << 2) + 3][t];
      *(float4*)(out_alpha + (size_t)t * VOCAB + vb + (vq << 2)) = a;
    }
  }

  // ---- phase 3: mu + P. thread owns d in {dg, dg+128}, v in vh*8..vh*8+7 ----
  const int dg = tid & 127, vh = tid >> 7;
  float acc2[2][8];
#pragma unroll
  for (int h = 0; h < 2; ++h)
#pragma unroll
    for (int j = 0; j < 8; ++j) acc2[h][j] = 0.f;

  for (int t4 = 0; t4 < 128; ++t4) {
    const int t = t4 << 2;
    float a0[4], a1[4];
#pragma unroll
    for (int q = 0; q < 4; ++q) {
      const float* p = AtT + (size_t)(t + q) * VDIM + dg;
      a0[q] = p[0];
      a1[q] = p[128];
    }
#pragma unroll
    for (int j = 0; j < 8; ++j) {
      float4 pv = *(const float4*)&S[(vh << 3) + j][t];
      acc2[0][j] += a0[0] * pv.x + a0[1] * pv.y + a0[2] * pv.z + a0[3] * pv.w;
      acc2[1][j] += a1[0] * pv.x + a1[1] * pv.y + a1[2] * pv.z + a1[3] * pv.w;
    }
  }

  const float inv_sigma = 1.0f / sigma[0];
  float pp[8];
#pragma unroll
  for (int j = 0; j < 8; ++j) {
    const int v = (vh << 3) + j;
    float d0 = W[v][dg]       - acc2[0][j];
    float d1 = W[v][dg + 128] - acc2[1][j];
    pp[j] = d0 * d0 + d1 * d1;
  }
#pragma unroll
  for (int j = 0; j < 8; ++j) {
    float x = pp[j];
#pragma unroll
    for (int off = 32; off > 0; off >>= 1) x += __shfl_xor(x, off);
    pp[j] = x;
  }
  if (lane == 0) {
#pragma unroll
    for (int j = 0; j < 8; ++j) red[(vh << 3) + j][wave] = pp[j];
  }
  __syncthreads();
  if (tid < 16) {
    const int w0 = (tid >> 3) << 1;  // v<8 -> waves 0,1 ; v>=8 -> waves 2,3
    out_P[vb + tid] = (red[tid][w0] + red[tid][w0 + 1]) * inv_sigma;
  }
}

// ---------------------------------------------------------------------------
// RL pass 1: per-topic rowsum and sum-of-squares over alpha (deterministic).
// ---------------------------------------------------------------------------
__global__ __launch_bounds__(256) void row_reduce(
    const float* __restrict__ alpha, float* __restrict__ rowsum, float* __restrict__ ssum)
{
  const int t = blockIdx.x;
  const float4* base = (const float4*)(alpha + (size_t)t * VOCAB);
  float rs = 0.f, ss = 0.f;
  for (int i = threadIdx.x; i < VOCAB / 4; i += 256) {
    float4 a = base[i];
    rs += a.x + a.y + a.z + a.w;
    ss += a.x * a.x + a.y * a.y + a.z * a.z + a.w * a.w;
  }
  __shared__ float lr[4], ls[4];
  const int lane = threadIdx.x & 63, wave = threadIdx.x >> 6;
#pragma unroll
  for (int off = 32; off > 0; off >>= 1) {
    rs += __shfl_xor(rs, off);
    ss += __shfl_xor(ss, off);
  }
  if (lane == 0) { lr[wave] = rs; ls[wave] = ss; }
  __syncthreads();
  if (threadIdx.x == 0) {
    rowsum[t] = lr[0] + lr[1] + lr[2] + lr[3];
    ssum[t]   = ls[0] + ls[1] + ls[2] + ls[3];
  }
}

// ---------------------------------------------------------------------------
// RL finalize: RL = sum_t ss_t - (sum_t rowsum_t^2)/VOCAB ; also copy sigma.
// ---------------------------------------------------------------------------
__global__ __launch_bounds__(512) void rl_final(
    const float* __restrict__ rowsum, const float* __restrict__ ssum,
    const float* __restrict__ sigma, float* __restrict__ out_RL,
    float* __restrict__ out_sigma)
{
  const int t = threadIdx.x;
  float a = ssum[t];
  float b = rowsum[t] * rowsum[t];
  __shared__ float la[8], lb[8];
  const int lane = t & 63, wave = t >> 6;
#pragma unroll
  for (int off = 32; off > 0; off >>= 1) {
    a += __shfl_xor(a, off);
    b += __shfl_xor(b, off);
  }
  if (lane == 0) { la[wave] = a; lb[wave] = b; }
  __syncthreads();
  if (t == 0) {
    float sa = 0.f, sb = 0.f;
#pragma unroll
    for (int w = 0; w < 8; ++w) { sa += la[w]; sb += lb[w]; }
    out_RL[0] = sa - sb / (float)VOCAB;
    out_sigma[0] = sigma[0];
  }
}

extern "C" void kernel_launch(void* const* d_in, const int* in_sizes, int n_in,
                              void* d_out, int out_size, void* d_ws, size_t ws_size,
                              hipStream_t stream) {
  const float* w2v   = (const float*)d_in[0];  // [50000][256]
  const float* t2v   = (const float*)d_in[1];  // [512][256]
  const float* A     = (const float*)d_in[2];  // [256][256]
  const float* B     = (const float*)d_in[3];  // [256][256]
  const float* sigma = (const float*)d_in[4];  // [1]

  float* out       = (float*)d_out;
  float* out_alpha = out;                                  // 25,600,000
  float* out_P     = out + (size_t)TOPICS * VOCAB;         // 50,000
  float* out_RL    = out_P + VOCAB;                        // 1
  float* out_s     = out_RL + 1;                           // 25,600,000
  float* out_sigma = out_s + (size_t)TOPICS * VOCAB;       // 1

  float* ws     = (float*)d_ws;
  float* tBT    = ws;                          // 256*512
  float* AtT    = tBT + (size_t)VDIM * TOPICS; // 512*256
  float* rowsum = AtT + (size_t)TOPICS * VDIM; // 512
  float* ssum   = rowsum + TOPICS;             // 512

  precompute_kernel<<<VDIM + TOPICS, 512, 0, stream>>>(t2v, A, B, tBT, AtT);
  fused_main<<<VOCAB / 16, 256, 0, stream>>>(w2v, tBT, AtT, sigma,
                                             out_alpha, out_P, out_s);
  row_reduce<<<TOPICS, 256, 0, stream>>>(out_alpha, rowsum, ssum);
  rl_final<<<1, 512, 0, stream>>>(rowsum, ssum, sigma, out_RL, out_sigma);
}

// Round 2
// 316.472 us; speedup vs baseline: 1.7330x; 1.7330x over previous
//
#include <hip/hip_runtime.h>

#define VOCAB 50000
#define VDIM 256
#define TOPICS 512
#define VT 32

typedef unsigned int uint;
typedef unsigned short ushort;
using short8 = __attribute__((ext_vector_type(8))) short;
using f32x4  = __attribute__((ext_vector_type(4))) float;

__device__ __forceinline__ ushort bf16_rne(float f) {
  uint u = __float_as_uint(f);
  u += 0x7FFFu + ((u >> 16) & 1u);
  return (ushort)(u >> 16);
}
__device__ __forceinline__ float bf16f(ushort h) {
  return __uint_as_float(((uint)h) << 16);
}
__device__ __forceinline__ uint packbf2(float a, float b) {
  return (uint)bf16_rne(a) | ((uint)bf16_rne(b) << 16);
}

// ---------------------------------------------------------------------------
// Precompute (hi/lo bf16 split):
//   tB[t][d] = sum_k t2v[t,k]*B[d,k]   -> tB_hi/tB_lo [512][256]
//   At[d][t] = sum_k A[d,k]*t2v[t,k]   -> At_hi/At_lo [256][512]
// ---------------------------------------------------------------------------
__global__ __launch_bounds__(512) void precompute(
    const float* __restrict__ t2v, const float* __restrict__ A,
    const float* __restrict__ B,
    ushort* __restrict__ tB_hi, ushort* __restrict__ tB_lo,
    ushort* __restrict__ At_hi, ushort* __restrict__ At_lo)
{
  __shared__ float row[256];
  const int b = blockIdx.x, tid = threadIdx.x;
  if (b < TOPICS) {
    if (tid < 256) row[tid] = t2v[(size_t)b * 256 + tid];
    __syncthreads();
    if (tid < 256) {
      const float4* rv = (const float4*)row;
      const float4* bv = (const float4*)(B + (size_t)tid * 256);
      float acc = 0.f;
#pragma unroll 8
      for (int k = 0; k < 64; ++k) {
        float4 r = rv[k], x = bv[k];
        acc += r.x * x.x + r.y * x.y + r.z * x.z + r.w * x.w;
      }
      ushort hi = bf16_rne(acc);
      ushort lo = bf16_rne(acc - bf16f(hi));
      tB_hi[(size_t)b * 256 + tid] = hi;
      tB_lo[(size_t)b * 256 + tid] = lo;
    }
  } else {
    const int d = b - TOPICS;
    if (tid < 256) row[tid] = A[(size_t)d * 256 + tid];
    __syncthreads();
    const float4* rv = (const float4*)row;
    const float4* tv = (const float4*)(t2v + (size_t)tid * 256);
    float acc = 0.f;
#pragma unroll 8
    for (int k = 0; k < 64; ++k) {
      float4 r = rv[k], x = tv[k];
      acc += r.x * x.x + r.y * x.y + r.z * x.z + r.w * x.w;
    }
    ushort hi = bf16_rne(acc);
    ushort lo = bf16_rne(acc - bf16f(hi));
    At_hi[(size_t)d * 512 + tid] = hi;
    At_lo[(size_t)d * 512 + tid] = lo;
  }
}

// ---------------------------------------------------------------------------
// Fused main: VT=32 vocab columns per block, 256 threads (4 waves).
//  s-GEMM (MFMA, 3-term split) -> write s -> reg softmax -> write alpha
//  -> alpha bf16 to LDS -> mu-GEMM (MFMA, 2-term) -> P.
// Per wave (s):  8 m-frags (128 topics) x 2 n-frags (32 vocab), K=256.
// Per wave (mu): 4 m-frags (64 dims)    x 2 n-frags (32 vocab), K=512.
// ---------------------------------------------------------------------------
__global__ __launch_bounds__(256, 2) void fused_main(
    const float* __restrict__ w2v,
    const ushort* __restrict__ tB_hi, const ushort* __restrict__ tB_lo,
    const ushort* __restrict__ At_hi, const ushort* __restrict__ At_lo,
    const float* __restrict__ sigma,
    float* __restrict__ out_alpha, float* __restrict__ out_P,
    float* __restrict__ out_s)
{
  __shared__ ushort Whi[VT][264];   // pitch 264 bf16 = 528 B: bank step 4, b128-aligned
  __shared__ ushort Wlo[VT][264];
  __shared__ ushort PA[VT][520];    // alpha bf16 [v][t], pitch 520 = 1040 B
  __shared__ float red[4][VT];

  const int tid  = threadIdx.x;
  const int wave = tid >> 6, lane = tid & 63;
  const int lr = lane & 15, lg = lane >> 4;
  const int vb = blockIdx.x * VT;

  // ---- stage W hi/lo (32 rows x 256 dims) ----
#pragma unroll
  for (int it = 0; it < 8; ++it) {
    int j = tid + (it << 8);
    int v = j >> 6, q = j & 63;
    int vr = min(vb + v, VOCAB - 1);
    float4 x = *(const float4*)(w2v + (size_t)vr * 256 + (q << 2));
    float xs[4] = {x.x, x.y, x.z, x.w};
    ushort h[4], l[4];
#pragma unroll
    for (int i = 0; i < 4; ++i) {
      ushort hi = bf16_rne(xs[i]);
      h[i] = hi;
      l[i] = bf16_rne(xs[i] - bf16f(hi));
    }
    *(uint2*)&Whi[v][q << 2] = make_uint2((uint)h[0] | ((uint)h[1] << 16),
                                          (uint)h[2] | ((uint)h[3] << 16));
    *(uint2*)&Wlo[v][q << 2] = make_uint2((uint)l[0] | ((uint)l[1] << 16),
                                          (uint)l[2] | ((uint)l[3] << 16));
  }
  __syncthreads();

  // ---- s-GEMM: acc[mi][nj] = s[t][v] frags ----
  f32x4 acc[8][2];
#pragma unroll
  for (int mi = 0; mi < 8; ++mi)
#pragma unroll
    for (int nj = 0; nj < 2; ++nj) acc[mi][nj] = (f32x4){0.f, 0.f, 0.f, 0.f};

  const int trow = (wave << 7) + lr;
#pragma unroll 2
  for (int ks = 0; ks < 8; ++ks) {
    const int k0 = (ks << 5) + (lg << 3);
    short8 bh[2], bl[2];
#pragma unroll
    for (int nj = 0; nj < 2; ++nj) {
      bh[nj] = *(const short8*)&Whi[(nj << 4) + lr][k0];
      bl[nj] = *(const short8*)&Wlo[(nj << 4) + lr][k0];
    }
#pragma unroll
    for (int mi = 0; mi < 8; ++mi) {
      const size_t aoff = (size_t)(trow + (mi << 4)) * 256 + k0;
      short8 ah = *(const short8*)(tB_hi + aoff);
      short8 al = *(const short8*)(tB_lo + aoff);
#pragma unroll
      for (int nj = 0; nj < 2; ++nj) {
        acc[mi][nj] = __builtin_amdgcn_mfma_f32_16x16x32_bf16(ah, bh[nj], acc[mi][nj], 0, 0, 0);
        acc[mi][nj] = __builtin_amdgcn_mfma_f32_16x16x32_bf16(al, bh[nj], acc[mi][nj], 0, 0, 0);
        acc[mi][nj] = __builtin_amdgcn_mfma_f32_16x16x32_bf16(ah, bl[nj], acc[mi][nj], 0, 0, 0);
      }
    }
  }

  // ---- write s (D layout: col = lr, row = lg*4 + r) ----
#pragma unroll
  for (int mi = 0; mi < 8; ++mi) {
    const int t = (wave << 7) + (mi << 4) + (lg << 2);
#pragma unroll
    for (int r = 0; r < 4; ++r)
#pragma unroll
      for (int nj = 0; nj < 2; ++nj) {
        const int v = vb + (nj << 4) + lr;
        if (v < VOCAB) out_s[(size_t)(t + r) * VOCAB + v] = acc[mi][nj][r];
      }
  }

  // ---- softmax over t per column ----
  float gmax[2];
  {
    float pm[2] = {-3.4e38f, -3.4e38f};
#pragma unroll
    for (int mi = 0; mi < 8; ++mi)
#pragma unroll
      for (int nj = 0; nj < 2; ++nj)
#pragma unroll
        for (int r = 0; r < 4; ++r) pm[nj] = fmaxf(pm[nj], acc[mi][nj][r]);
#pragma unroll
    for (int nj = 0; nj < 2; ++nj) {
      pm[nj] = fmaxf(pm[nj], __shfl_xor(pm[nj], 16));
      pm[nj] = fmaxf(pm[nj], __shfl_xor(pm[nj], 32));
    }
    if (lg == 0) { red[wave][lr] = pm[0]; red[wave][16 + lr] = pm[1]; }
  }
  __syncthreads();
#pragma unroll
  for (int nj = 0; nj < 2; ++nj) {
    const int c = (nj << 4) + lr;
    gmax[nj] = fmaxf(fmaxf(red[0][c], red[1][c]), fmaxf(red[2][c], red[3][c]));
  }
  __syncthreads();

  float inv[2];
  {
    float ps[2] = {0.f, 0.f};
#pragma unroll
    for (int mi = 0; mi < 8; ++mi)
#pragma unroll
      for (int nj = 0; nj < 2; ++nj)
#pragma unroll
        for (int r = 0; r < 4; ++r) {
          float e = __expf(acc[mi][nj][r] - gmax[nj]);
          acc[mi][nj][r] = e;
          ps[nj] += e;
        }
#pragma unroll
    for (int nj = 0; nj < 2; ++nj) {
      ps[nj] += __shfl_xor(ps[nj], 16);
      ps[nj] += __shfl_xor(ps[nj], 32);
    }
    if (lg == 0) { red[wave][lr] = ps[0]; red[wave][16 + lr] = ps[1]; }
  }
  __syncthreads();
#pragma unroll
  for (int nj = 0; nj < 2; ++nj) {
    const int c = (nj << 4) + lr;
    inv[nj] = 1.0f / (red[0][c] + red[1][c] + red[2][c] + red[3][c]);
  }

  // ---- alpha = exp*inv: write fp32 to global, bf16 to LDS ----
#pragma unroll
  for (int mi = 0; mi < 8; ++mi) {
    const int tb = (wave << 7) + (mi << 4) + (lg << 2);
#pragma unroll
    for (int nj = 0; nj < 2; ++nj) {
#pragma unroll
      for (int r = 0; r < 4; ++r) acc[mi][nj][r] *= inv[nj];
      const int v = vb + (nj << 4) + lr;
      if (v < VOCAB) {
#pragma unroll
        for (int r = 0; r < 4; ++r)
          out_alpha[(size_t)(tb + r) * VOCAB + v] = acc[mi][nj][r];
      }
      uint2 pw;
      pw.x = packbf2(acc[mi][nj][0], acc[mi][nj][1]);
      pw.y = packbf2(acc[mi][nj][2], acc[mi][nj][3]);
      *(uint2*)&PA[(nj << 4) + lr][tb] = pw;
    }
  }
  __syncthreads();

  // ---- mu-GEMM: macc[mi][nj] = mu[d][v] frags (K = 512 topics) ----
  f32x4 macc[4][2];
#pragma unroll
  for (int mi = 0; mi < 4; ++mi)
#pragma unroll
    for (int nj = 0; nj < 2; ++nj) macc[mi][nj] = (f32x4){0.f, 0.f, 0.f, 0.f};

  const int drow = (wave << 6) + lr;
#pragma unroll 2
  for (int ks = 0; ks < 16; ++ks) {
    const int k0 = (ks << 5) + (lg << 3);
    short8 pb[2];
#pragma unroll
    for (int nj = 0; nj < 2; ++nj)
      pb[nj] = *(const short8*)&PA[(nj << 4) + lr][k0];
#pragma unroll
    for (int mi = 0; mi < 4; ++mi) {
      const size_t aoff = (size_t)(drow + (mi << 4)) * 512 + k0;
      short8 ah = *(const short8*)(At_hi + aoff);
      short8 al = *(const short8*)(At_lo + aoff);
#pragma unroll
      for (int nj = 0; nj < 2; ++nj) {
        macc[mi][nj] = __builtin_amdgcn_mfma_f32_16x16x32_bf16(ah, pb[nj], macc[mi][nj], 0, 0, 0);
        macc[mi][nj] = __builtin_amdgcn_mfma_f32_16x16x32_bf16(al, pb[nj], macc[mi][nj], 0, 0, 0);
      }
    }
  }

  // ---- P: sum_d (w2v - mu)^2 per column ----
  {
    float pp[2] = {0.f, 0.f};
#pragma unroll
    for (int mi = 0; mi < 4; ++mi) {
      const int dbase = (wave << 6) + (mi << 4) + (lg << 2);
#pragma unroll
      for (int nj = 0; nj < 2; ++nj) {
        const int v = (nj << 4) + lr;
        uint2 wh = *(const uint2*)&Whi[v][dbase];
        uint2 wl = *(const uint2*)&Wlo[v][dbase];
        float w0 = bf16f((ushort)(wh.x & 0xFFFF)) + bf16f((ushort)(wl.x & 0xFFFF));
        float w1 = bf16f((ushort)(wh.x >> 16))    + bf16f((ushort)(wl.x >> 16));
        float w2 = bf16f((ushort)(wh.y & 0xFFFF)) + bf16f((ushort)(wl.y & 0xFFFF));
        float w3 = bf16f((ushort)(wh.y >> 16))    + bf16f((ushort)(wl.y >> 16));
        float d0 = w0 - macc[mi][nj][0];
        float d1 = w1 - macc[mi][nj][1];
        float d2 = w2 - macc[mi][nj][2];
        float d3 = w3 - macc[mi][nj][3];
        pp[nj] += d0 * d0 + d1 * d1 + d2 * d2 + d3 * d3;
      }
    }
#pragma unroll
    for (int nj = 0; nj < 2; ++nj) {
      pp[nj] += __shfl_xor(pp[nj], 16);
      pp[nj] += __shfl_xor(pp[nj], 32);
    }
    if (lg == 0) { red[wave][lr] = pp[0]; red[wave][16 + lr] = pp[1]; }
  }
  __syncthreads();
  if (tid < VT) {
    float sum = red[0][tid] + red[1][tid] + red[2][tid] + red[3][tid];
    const int v = vb + tid;
    if (v < VOCAB) out_P[v] = sum / sigma[0];
  }
}

// ---------------------------------------------------------------------------
// RL pass 1: per-topic rowsum and sum-of-squares over alpha (deterministic).
// ---------------------------------------------------------------------------
__global__ __launch_bounds__(256) void row_reduce(
    const float* __restrict__ alpha, float* __restrict__ rowsum, float* __restrict__ ssum)
{
  const int t = blockIdx.x;
  const float4* base = (const float4*)(alpha + (size_t)t * VOCAB);
  float rs = 0.f, ss = 0.f;
  for (int i = threadIdx.x; i < VOCAB / 4; i += 256) {
    float4 a = base[i];
    rs += a.x + a.y + a.z + a.w;
    ss += a.x * a.x + a.y * a.y + a.z * a.z + a.w * a.w;
  }
  __shared__ float lr[4], ls[4];
  const int lane = threadIdx.x & 63, wave = threadIdx.x >> 6;
#pragma unroll
  for (int off = 32; off > 0; off >>= 1) {
    rs += __shfl_xor(rs, off);
    ss += __shfl_xor(ss, off);
  }
  if (lane == 0) { lr[wave] = rs; ls[wave] = ss; }
  __syncthreads();
  if (threadIdx.x == 0) {
    rowsum[t] = lr[0] + lr[1] + lr[2] + lr[3];
    ssum[t]   = ls[0] + ls[1] + ls[2] + ls[3];
  }
}

__global__ __launch_bounds__(512) void rl_final(
    const float* __restrict__ rowsum, const float* __restrict__ ssum,
    const float* __restrict__ sigma, float* __restrict__ out_RL,
    float* __restrict__ out_sigma)
{
  const int t = threadIdx.x;
  float a = ssum[t];
  float b = rowsum[t] * rowsum[t];
  __shared__ float la[8], lb[8];
  const int lane = t & 63, wave = t >> 6;
#pragma unroll
  for (int off = 32; off > 0; off >>= 1) {
    a += __shfl_xor(a, off);
    b += __shfl_xor(b, off);
  }
  if (lane == 0) { la[wave] = a; lb[wave] = b; }
  __syncthreads();
  if (t == 0) {
    float sa = 0.f, sb = 0.f;
#pragma unroll
    for (int w = 0; w < 8; ++w) { sa += la[w]; sb += lb[w]; }
    out_RL[0] = sa - sb / (float)VOCAB;
    out_sigma[0] = sigma[0];
  }
}

extern "C" void kernel_launch(void* const* d_in, const int* in_sizes, int n_in,
                              void* d_out, int out_size, void* d_ws, size_t ws_size,
                              hipStream_t stream) {
  const float* w2v   = (const float*)d_in[0];  // [50000][256]
  const float* t2v   = (const float*)d_in[1];  // [512][256]
  const float* A     = (const float*)d_in[2];  // [256][256]
  const float* B     = (const float*)d_in[3];  // [256][256]
  const float* sigma = (const float*)d_in[4];  // [1]

  float* out       = (float*)d_out;
  float* out_alpha = out;                                  // 25,600,000
  float* out_P     = out + (size_t)TOPICS * VOCAB;         // 50,000
  float* out_RL    = out_P + VOCAB;                        // 1
  float* out_s     = out_RL + 1;                           // 25,600,000
  float* out_sigma = out_s + (size_t)TOPICS * VOCAB;       // 1

  ushort* tB_hi = (ushort*)d_ws;                           // 512*256
  ushort* tB_lo = tB_hi + (size_t)TOPICS * VDIM;
  ushort* At_hi = tB_lo + (size_t)TOPICS * VDIM;           // 256*512
  ushort* At_lo = At_hi + (size_t)VDIM * TOPICS;
  float* rowsum = (float*)(At_lo + (size_t)VDIM * TOPICS);
  float* ssum   = rowsum + TOPICS;

  precompute<<<TOPICS + VDIM, 512, 0, stream>>>(t2v, A, B, tB_hi, tB_lo, At_hi, At_lo);

  const int nblocks = (VOCAB + VT - 1) / VT;  // 1563
  fused_main<<<nblocks, 256, 0, stream>>>(w2v, tB_hi, tB_lo, At_hi, At_lo, sigma,
                                          out_alpha, out_P, out_s);

  row_reduce<<<TOPICS, 256, 0, stream>>>(out_alpha, rowsum, ssum);
  rl_final<<<1, 512, 0, stream>>>(rowsum, ssum, sigma, out_RL, out_sigma);
}

// Round 3
// 211.300 us; speedup vs baseline: 2.5955x; 1.4977x over previous
//
#include <hip/hip_runtime.h>

#define VOCAB 50000
#define VDIM 256
#define TOPICS 512
#define VT 32

typedef unsigned int uint;
typedef unsigned short ushort;
using short8 = __attribute__((ext_vector_type(8))) short;
using f32x4  = __attribute__((ext_vector_type(4))) float;

__device__ __forceinline__ ushort bf16_rne(float f) {
  uint u = __float_as_uint(f);
  u += 0x7FFFu + ((u >> 16) & 1u);
  return (ushort)(u >> 16);
}
__device__ __forceinline__ float bf16f(ushort h) {
  return __uint_as_float(((uint)h) << 16);
}
__device__ __forceinline__ uint packbf2(float a, float b) {
  return (uint)bf16_rne(a) | ((uint)bf16_rne(b) << 16);
}

// ---------------------------------------------------------------------------
// Precompute with fragment-major packing (hi/lo bf16 split):
//   tB[t][d] = sum_k t2v[t,k]*B[d,k]
//     packed tBp[tile=t>>4][ks=d>>5][hl][lane=(t&15)|(((d>>3)&3)<<4)][e=d&7]
//   At[d][t] = sum_k A[d,k]*t2v[t,k]
//     packed Atp[dtile=d>>4][ks=t>>5][hl][lane=(d&15)|(((t>>3)&3)<<4)][e=t&7]
// Each wave-load in fused_main is then one coalesced 1KB dwordx4.
// ---------------------------------------------------------------------------
__global__ __launch_bounds__(512) void precompute(
    const float* __restrict__ t2v, const float* __restrict__ A,
    const float* __restrict__ B,
    ushort* __restrict__ tBp, ushort* __restrict__ Atp)
{
  __shared__ float row[256];
  const int b = blockIdx.x, tid = threadIdx.x;
  if (b < TOPICS) {
    const int t = b;
    if (tid < 256) row[tid] = t2v[(size_t)t * 256 + tid];
    __syncthreads();
    if (tid < 256) {
      const int d = tid;
      const float4* rv = (const float4*)row;
      const float4* bv = (const float4*)(B + (size_t)d * 256);
      float acc = 0.f;
#pragma unroll 8
      for (int k = 0; k < 64; ++k) {
        float4 r = rv[k], x = bv[k];
        acc += r.x * x.x + r.y * x.y + r.z * x.z + r.w * x.w;
      }
      ushort hi = bf16_rne(acc);
      ushort lo = bf16_rne(acc - bf16f(hi));
      const int tile = t >> 4, ks = d >> 5;
      const int lane = (t & 15) | (((d >> 3) & 3) << 4);
      const int e = d & 7;
      size_t base = ((size_t)(tile * 8 + ks) * 2) * 512 + lane * 8 + e;
      tBp[base]       = hi;
      tBp[base + 512] = lo;
    }
  } else {
    const int d = b - TOPICS;
    if (tid < 256) row[tid] = A[(size_t)d * 256 + tid];
    __syncthreads();
    const int t = tid;
    const float4* rv = (const float4*)row;
    const float4* tv = (const float4*)(t2v + (size_t)t * 256);
    float acc = 0.f;
#pragma unroll 8
    for (int k = 0; k < 64; ++k) {
      float4 r = rv[k], x = tv[k];
      acc += r.x * x.x + r.y * x.y + r.z * x.z + r.w * x.w;
    }
    ushort hi = bf16_rne(acc);
    ushort lo = bf16_rne(acc - bf16f(hi));
    const int dtile = d >> 4, ks = t >> 5;
    const int lane = (d & 15) | (((t >> 3) & 3) << 4);
    const int e = t & 7;
    size_t base = ((size_t)(dtile * 16 + ks) * 2) * 512 + lane * 8 + e;
    Atp[base]       = hi;
    Atp[base + 512] = lo;
  }
}

// ---------------------------------------------------------------------------
// Fused main: VT=32 vocab columns per block, 256 threads (4 waves).
// LDS: PA aliases Whi/Wlo (W is dead after s-GEMM; P re-reads w2v from L2).
// 34.3KB LDS -> 4 blocks/CU. A-operands: packed coalesced + depth-2 prefetch.
// ---------------------------------------------------------------------------
__global__ __launch_bounds__(256, 4) void fused_main(
    const float* __restrict__ w2v,
    const ushort* __restrict__ tBp, const ushort* __restrict__ Atp,
    const float* __restrict__ sigma,
    float* __restrict__ out_alpha, float* __restrict__ out_P,
    float* __restrict__ out_s)
{
  __shared__ __align__(16) char smem[33792];
  ushort (*Whi)[264] = (ushort (*)[264])smem;            // 16896 B
  ushort (*Wlo)[264] = (ushort (*)[264])(smem + 16896);  // 16896 B
  ushort (*PA)[520]  = (ushort (*)[520])smem;            // 33280 B (alias)
  __shared__ float red[4][VT];

  const int tid  = threadIdx.x;
  const int wave = tid >> 6, lane = tid & 63;
  const int lr = lane & 15, lg = lane >> 4;
  const int vb = blockIdx.x * VT;

  // ---- stage W hi/lo (32 rows x 256 dims) ----
#pragma unroll
  for (int it = 0; it < 8; ++it) {
    int j = tid + (it << 8);
    int v = j >> 6, q = j & 63;
    int vr = min(vb + v, VOCAB - 1);
    float4 x = *(const float4*)(w2v + (size_t)vr * 256 + (q << 2));
    float xs[4] = {x.x, x.y, x.z, x.w};
    ushort h[4], l[4];
#pragma unroll
    for (int i = 0; i < 4; ++i) {
      ushort hi = bf16_rne(xs[i]);
      h[i] = hi;
      l[i] = bf16_rne(xs[i] - bf16f(hi));
    }
    *(uint2*)&Whi[v][q << 2] = make_uint2((uint)h[0] | ((uint)h[1] << 16),
                                          (uint)h[2] | ((uint)h[3] << 16));
    *(uint2*)&Wlo[v][q << 2] = make_uint2((uint)l[0] | ((uint)l[1] << 16),
                                          (uint)l[2] | ((uint)l[3] << 16));
  }
  __syncthreads();

  // ---- s-GEMM: acc[mi][nj], t-rows = wave*128 + mi*16 + lr ----
  f32x4 acc[8][2];
#pragma unroll
  for (int mi = 0; mi < 8; ++mi)
#pragma unroll
    for (int nj = 0; nj < 2; ++nj) acc[mi][nj] = (f32x4){0.f, 0.f, 0.f, 0.f};

#pragma unroll
  for (int ks = 0; ks < 8; ++ks) {
    const int k0 = (ks << 5) + (lg << 3);
    short8 bh[2], bl[2];
#pragma unroll
    for (int nj = 0; nj < 2; ++nj) {
      bh[nj] = *(const short8*)&Whi[(nj << 4) + lr][k0];
      bl[nj] = *(const short8*)&Wlo[(nj << 4) + lr][k0];
    }
    // packed A base: tile = wave*8 + mi; stride per tile = 8ks*2*512 = 8192
    const ushort* abase = tBp + ((size_t)(wave * 8) * 8 + ks) * 1024 + lane * 8;
    short8 ahp[2], alp[2];
    ahp[0] = *(const short8*)(abase);
    alp[0] = *(const short8*)(abase + 512);
    ahp[1] = *(const short8*)(abase + 8192);
    alp[1] = *(const short8*)(abase + 8192 + 512);
#pragma unroll
    for (int mi = 0; mi < 8; ++mi) {
      short8 ah = ahp[mi & 1], al = alp[mi & 1];
      if (mi < 6) {
        ahp[mi & 1] = *(const short8*)(abase + (size_t)(mi + 2) * 8192);
        alp[mi & 1] = *(const short8*)(abase + (size_t)(mi + 2) * 8192 + 512);
      }
#pragma unroll
      for (int nj = 0; nj < 2; ++nj) {
        acc[mi][nj] = __builtin_amdgcn_mfma_f32_16x16x32_bf16(ah, bh[nj], acc[mi][nj], 0, 0, 0);
        acc[mi][nj] = __builtin_amdgcn_mfma_f32_16x16x32_bf16(al, bh[nj], acc[mi][nj], 0, 0, 0);
        acc[mi][nj] = __builtin_amdgcn_mfma_f32_16x16x32_bf16(ah, bl[nj], acc[mi][nj], 0, 0, 0);
      }
    }
  }

  // ---- write s (D layout: col = lr, row = lg*4 + r) ----
#pragma unroll
  for (int mi = 0; mi < 8; ++mi) {
    const int t = (wave << 7) + (mi << 4) + (lg << 2);
#pragma unroll
    for (int r = 0; r < 4; ++r)
#pragma unroll
      for (int nj = 0; nj < 2; ++nj) {
        const int v = vb + (nj << 4) + lr;
        if (v < VOCAB) out_s[(size_t)(t + r) * VOCAB + v] = acc[mi][nj][r];
      }
  }

  // ---- softmax over t per column ----
  float gmax[2];
  {
    float pm[2] = {-3.4e38f, -3.4e38f};
#pragma unroll
    for (int mi = 0; mi < 8; ++mi)
#pragma unroll
      for (int nj = 0; nj < 2; ++nj)
#pragma unroll
        for (int r = 0; r < 4; ++r) pm[nj] = fmaxf(pm[nj], acc[mi][nj][r]);
#pragma unroll
    for (int nj = 0; nj < 2; ++nj) {
      pm[nj] = fmaxf(pm[nj], __shfl_xor(pm[nj], 16));
      pm[nj] = fmaxf(pm[nj], __shfl_xor(pm[nj], 32));
    }
    if (lg == 0) { red[wave][lr] = pm[0]; red[wave][16 + lr] = pm[1]; }
  }
  __syncthreads();
#pragma unroll
  for (int nj = 0; nj < 2; ++nj) {
    const int c = (nj << 4) + lr;
    gmax[nj] = fmaxf(fmaxf(red[0][c], red[1][c]), fmaxf(red[2][c], red[3][c]));
  }
  __syncthreads();

  float inv[2];
  {
    float ps[2] = {0.f, 0.f};
#pragma unroll
    for (int mi = 0; mi < 8; ++mi)
#pragma unroll
      for (int nj = 0; nj < 2; ++nj)
#pragma unroll
        for (int r = 0; r < 4; ++r) {
          float e = __expf(acc[mi][nj][r] - gmax[nj]);
          acc[mi][nj][r] = e;
          ps[nj] += e;
        }
#pragma unroll
    for (int nj = 0; nj < 2; ++nj) {
      ps[nj] += __shfl_xor(ps[nj], 16);
      ps[nj] += __shfl_xor(ps[nj], 32);
    }
    if (lg == 0) { red[wave][lr] = ps[0]; red[wave][16 + lr] = ps[1]; }
  }
  __syncthreads();
#pragma unroll
  for (int nj = 0; nj < 2; ++nj) {
    const int c = (nj << 4) + lr;
    inv[nj] = 1.0f / (red[0][c] + red[1][c] + red[2][c] + red[3][c]);
  }
  __syncthreads();   // red reads done; also last Whi/Wlo reads were in s-loop

  // ---- alpha = exp*inv: write fp32 to global, bf16 to LDS (PA aliases W) ----
#pragma unroll
  for (int mi = 0; mi < 8; ++mi) {
    const int tb = (wave << 7) + (mi << 4) + (lg << 2);
#pragma unroll
    for (int nj = 0; nj < 2; ++nj) {
#pragma unroll
      for (int r = 0; r < 4; ++r) acc[mi][nj][r] *= inv[nj];
      const int v = vb + (nj << 4) + lr;
      if (v < VOCAB) {
#pragma unroll
        for (int r = 0; r < 4; ++r)
          out_alpha[(size_t)(tb + r) * VOCAB + v] = acc[mi][nj][r];
      }
      uint2 pw;
      pw.x = packbf2(acc[mi][nj][0], acc[mi][nj][1]);
      pw.y = packbf2(acc[mi][nj][2], acc[mi][nj][3]);
      *(uint2*)&PA[(nj << 4) + lr][tb] = pw;
    }
  }
  __syncthreads();

  // ---- mu-GEMM: macc[mi][nj], d-rows = wave*64 + mi*16 + lr, K=512 ----
  f32x4 macc[4][2];
#pragma unroll
  for (int mi = 0; mi < 4; ++mi)
#pragma unroll
    for (int nj = 0; nj < 2; ++nj) macc[mi][nj] = (f32x4){0.f, 0.f, 0.f, 0.f};

#pragma unroll
  for (int ks = 0; ks < 16; ++ks) {
    const int k0 = (ks << 5) + (lg << 3);
    short8 pb[2];
#pragma unroll
    for (int nj = 0; nj < 2; ++nj)
      pb[nj] = *(const short8*)&PA[(nj << 4) + lr][k0];
    // packed At base: dtile = wave*4 + mi; stride per dtile = 16ks*2*512 = 16384
    const ushort* abase = Atp + ((size_t)(wave * 4) * 16 + ks) * 1024 + lane * 8;
    short8 ahp[2], alp[2];
    ahp[0] = *(const short8*)(abase);
    alp[0] = *(const short8*)(abase + 512);
    ahp[1] = *(const short8*)(abase + 16384);
    alp[1] = *(const short8*)(abase + 16384 + 512);
#pragma unroll
    for (int mi = 0; mi < 4; ++mi) {
      short8 ah = ahp[mi & 1], al = alp[mi & 1];
      if (mi < 2) {
        ahp[mi & 1] = *(const short8*)(abase + (size_t)(mi + 2) * 16384);
        alp[mi & 1] = *(const short8*)(abase + (size_t)(mi + 2) * 16384 + 512);
      }
#pragma unroll
      for (int nj = 0; nj < 2; ++nj) {
        macc[mi][nj] = __builtin_amdgcn_mfma_f32_16x16x32_bf16(ah, pb[nj], macc[mi][nj], 0, 0, 0);
        macc[mi][nj] = __builtin_amdgcn_mfma_f32_16x16x32_bf16(al, pb[nj], macc[mi][nj], 0, 0, 0);
      }
    }
  }

  // ---- P: sum_d (w2v - mu)^2 per column (w2v re-read from global/L2) ----
  {
    float pp[2] = {0.f, 0.f};
#pragma unroll
    for (int mi = 0; mi < 4; ++mi) {
      const int dbase = (wave << 6) + (mi << 4) + (lg << 2);
#pragma unroll
      for (int nj = 0; nj < 2; ++nj) {
        const int vr = min(vb + (nj << 4) + lr, VOCAB - 1);
        float4 w = *(const float4*)(w2v + (size_t)vr * 256 + dbase);
        float d0 = w.x - macc[mi][nj][0];
        float d1 = w.y - macc[mi][nj][1];
        float d2 = w.z - macc[mi][nj][2];
        float d3 = w.w - macc[mi][nj][3];
        pp[nj] += d0 * d0 + d1 * d1 + d2 * d2 + d3 * d3;
      }
    }
#pragma unroll
    for (int nj = 0; nj < 2; ++nj) {
      pp[nj] += __shfl_xor(pp[nj], 16);
      pp[nj] += __shfl_xor(pp[nj], 32);
    }
    if (lg == 0) { red[wave][lr] = pp[0]; red[wave][16 + lr] = pp[1]; }
  }
  __syncthreads();
  if (tid < VT) {
    float sum = red[0][tid] + red[1][tid] + red[2][tid] + red[3][tid];
    const int v = vb + tid;
    if (v < VOCAB) out_P[v] = sum / sigma[0];
  }
}

// ---------------------------------------------------------------------------
// RL pass 1: per-topic rowsum and sum-of-squares over alpha (deterministic).
// ---------------------------------------------------------------------------
__global__ __launch_bounds__(256) void row_reduce(
    const float* __restrict__ alpha, float* __restrict__ rowsum, float* __restrict__ ssum)
{
  const int t = blockIdx.x;
  const float4* base = (const float4*)(alpha + (size_t)t * VOCAB);
  float rs = 0.f, ss = 0.f;
  for (int i = threadIdx.x; i < VOCAB / 4; i += 256) {
    float4 a = base[i];
    rs += a.x + a.y + a.z + a.w;
    ss += a.x * a.x + a.y * a.y + a.z * a.z + a.w * a.w;
  }
  __shared__ float lr[4], ls[4];
  const int lane = threadIdx.x & 63, wave = threadIdx.x >> 6;
#pragma unroll
  for (int off = 32; off > 0; off >>= 1) {
    rs += __shfl_xor(rs, off);
    ss += __shfl_xor(ss, off);
  }
  if (lane == 0) { lr[wave] = rs; ls[wave] = ss; }
  __syncthreads();
  if (threadIdx.x == 0) {
    rowsum[t] = lr[0] + lr[1] + lr[2] + lr[3];
    ssum[t]   = ls[0] + ls[1] + ls[2] + ls[3];
  }
}

__global__ __launch_bounds__(512) void rl_final(
    const float* __restrict__ rowsum, const float* __restrict__ ssum,
    const float* __restrict__ sigma, float* __restrict__ out_RL,
    float* __restrict__ out_sigma)
{
  const int t = threadIdx.x;
  float a = ssum[t];
  float b = rowsum[t] * rowsum[t];
  __shared__ float la[8], lb[8];
  const int lane = t & 63, wave = t >> 6;
#pragma unroll
  for (int off = 32; off > 0; off >>= 1) {
    a += __shfl_xor(a, off);
    b += __shfl_xor(b, off);
  }
  if (lane == 0) { la[wave] = a; lb[wave] = b; }
  __syncthreads();
  if (t == 0) {
    float sa = 0.f, sb = 0.f;
#pragma unroll
    for (int w = 0; w < 8; ++w) { sa += la[w]; sb += lb[w]; }
    out_RL[0] = sa - sb / (float)VOCAB;
    out_sigma[0] = sigma[0];
  }
}

extern "C" void kernel_launch(void* const* d_in, const int* in_sizes, int n_in,
                              void* d_out, int out_size, void* d_ws, size_t ws_size,
                              hipStream_t stream) {
  const float* w2v   = (const float*)d_in[0];  // [50000][256]
  const float* t2v   = (const float*)d_in[1];  // [512][256]
  const float* A     = (const float*)d_in[2];  // [256][256]
  const float* B     = (const float*)d_in[3];  // [256][256]
  const float* sigma = (const float*)d_in[4];  // [1]

  float* out       = (float*)d_out;
  float* out_alpha = out;                                  // 25,600,000
  float* out_P     = out + (size_t)TOPICS * VOCAB;         // 50,000
  float* out_RL    = out_P + VOCAB;                        // 1
  float* out_s     = out_RL + 1;                           // 25,600,000
  float* out_sigma = out_s + (size_t)TOPICS * VOCAB;       // 1

  ushort* tBp = (ushort*)d_ws;                             // 32*8*2*64*8   = 262144
  ushort* Atp = tBp + (size_t)262144;                      // 16*16*2*64*8  = 262144
  float* rowsum = (float*)(Atp + (size_t)262144);
  float* ssum   = rowsum + TOPICS;

  precompute<<<TOPICS + VDIM, 512, 0, stream>>>(t2v, A, B, tBp, Atp);

  const int nblocks = (VOCAB + VT - 1) / VT;  // 1563
  fused_main<<<nblocks, 256, 0, stream>>>(w2v, tBp, Atp, sigma,
                                          out_alpha, out_P, out_s);

  row_reduce<<<TOPICS, 256, 0, stream>>>(out_alpha, rowsum, ssum);
  rl_final<<<1, 512, 0, stream>>>(rowsum, ssum, sigma, out_RL, out_sigma);
}